// Round 1
// baseline (9519.351 us; speedup 1.0000x reference)
//
#include <hip/hip_runtime.h>

// 2-layer LSTM LM. V=5000 H=1024 E=512 B=64 T=256, future=0.
// Round-4 structure: replace 257 step_k launches with ONE persistent kernel.
//   - 256 blocks x 256 threads; blocks 0..127 = layer1 step t, 128..255 = layer2 step t-1.
//   - Weights held in LDS (layer1 96KB, layer2 128KB), XOR-swizzled rows (T2) so the
//     ds_read_b128 fragment reads are bank-conflict-free.
//   - 128KB LDS forces 1 block/CU => 256 blocks on 256 CUs are all co-resident =>
//     spin barrier (monotonic counter, never reset) is deadlock-safe without
//     cooperative launch. __threadfence() release/acquire for cross-XCD h visibility.
//   - pack/embed/gemm_out kernels unchanged from the harness-verified round-3 kernel.
// d_ws usage: ONLY h2a = (T+1)*B*H bf16 = 33.69 MB. Barrier counter lives in the free
// front region of d_out (dead until gemm_out runs).

#define V_ 5000
#define H_ 1024
#define E_ 512
#define B_ 64
#define T_ 256

// float-element offsets into d_out for staging that is dead before gemm_out.
// out_size = B*T*V = 81,920,000 floats; regions below fit exactly at the tail.
#define OFF_BAR  70180352   // 1 u32 barrier counter (free region, < OFF_W1P)
#define OFF_W1P  70180864   // 6,291,456 bf16  (4096x1536)
#define OFF_W2P  73326592   // 8,388,608 bf16  (4096x2048)
#define OFF_XEMB 77520896   // 8,388,608 bf16  (T*B*E)
#define OFF_H1B  81715200   // 131,072 bf16    (2 x B x H double buffer)
#define OFF_C1   81780736   // 65,536 fp32
#define OFF_C2   81846272   // 65,536 fp32
#define OFF_B1P  81911808   // 4,096 fp32
#define OFF_B2P  81915904   // 4,096 fp32      (ends exactly at 81,920,000)

#define LDS_BYTES 131072

typedef unsigned short ushort_t;
typedef __bf16 bf16x8 __attribute__((ext_vector_type(8)));
typedef unsigned short us8 __attribute__((ext_vector_type(8)));
typedef float f32x4 __attribute__((ext_vector_type(4)));

__device__ __forceinline__ ushort_t f2bf(float f) {  // RNE fp32->bf16
  unsigned int u = __float_as_uint(f);
  u += 0x7fffu + ((u >> 16) & 1u);
  return (ushort_t)(u >> 16);
}

__device__ __forceinline__ f32x4 mfma16(us8 a, us8 b, f32x4 c) {
  return __builtin_amdgcn_mfma_f32_16x16x32_bf16(
      __builtin_bit_cast(bf16x8, a), __builtin_bit_cast(bf16x8, b), c, 0, 0, 0);
}

__device__ __forceinline__ float sig_(float x) { return 1.f / (1.f + __expf(-x)); }
__device__ __forceinline__ float tanh_(float x) { return 2.f / (1.f + __expf(-2.f * x)) - 1.f; }

// ---------------- prep kernels ----------------

__global__ void zero_init(ushort_t* h1buf, float* c1, float* c2, ushort_t* h2s0,
                          unsigned int* bar) {
  int i = blockIdx.x * 256 + threadIdx.x;     // grid 512*256 = 131072
  if (i < 2 * B_ * H_) h1buf[i] = 0;
  if (i < B_ * H_) { c1[i] = 0.f; c2[i] = 0.f; h2s0[i] = 0; }
  if (i == 0) *bar = 0u;                      // re-zeroed every graph replay
}

// packed row p: blk=p>>5 owns units blk*8..+7; rl=p&31 = tile*16 + half*8 + (u&7),
// gate g = tile*2+half (0=i 1=f 2=g 3=o). Layer1 cols: [0,1024)=W_hh1, [1024,1536)=W_ih1.
__global__ void pack_w1(const float* __restrict__ Whh, const float* __restrict__ Wih,
                        const float* __restrict__ bi, const float* __restrict__ bh,
                        ushort_t* __restrict__ W1p, float* __restrict__ b1p) {
  int p = blockIdx.x;
  int rl = p & 31, blk = p >> 5;
  int g = ((rl >> 4) << 1) | ((rl >> 3) & 1);
  int u = (blk << 3) | (rl & 7);
  int sr = g * 1024 + u;
  for (int k = threadIdx.x; k < 1536; k += 256) {
    float v = (k < 1024) ? Whh[sr * 1024 + k] : Wih[sr * 512 + (k - 1024)];
    W1p[p * 1536 + k] = f2bf(v);
  }
  if (threadIdx.x == 0) b1p[p] = bi[sr] + bh[sr];
}

// Layer2 cols: [0,1024)=W_ih2 (input h1_t), [1024,2048)=W_hh2 (h2_{t-1}).
__global__ void pack_w2(const float* __restrict__ Wih, const float* __restrict__ Whh,
                        const float* __restrict__ bi, const float* __restrict__ bh,
                        ushort_t* __restrict__ W2p, float* __restrict__ b2p) {
  int p = blockIdx.x;
  int rl = p & 31, blk = p >> 5;
  int g = ((rl >> 4) << 1) | ((rl >> 3) & 1);
  int u = (blk << 3) | (rl & 7);
  int sr = g * 1024 + u;
  for (int k = threadIdx.x; k < 2048; k += 256) {
    float v = (k < 1024) ? Wih[sr * 1024 + k] : Whh[sr * 1024 + (k - 1024)];
    W2p[p * 2048 + k] = f2bf(v);
  }
  if (threadIdx.x == 0) b2p[p] = bi[sr] + bh[sr];
}

__global__ void embed_k(const int* __restrict__ inp, const float* __restrict__ emb,
                        ushort_t* __restrict__ xemb) {
  int tb = blockIdx.x;           // tb = t*64 + b
  int t = tb >> 6, b = tb & 63;
  int tok = inp[b * T_ + t];
  const float* src = emb + (long)tok * E_;
  ushort_t* dst = xemb + (long)tb * E_;
  for (int k = threadIdx.x; k < E_; k += 256) dst[k] = f2bf(src[k]);
}

// ---------------- persistent all-timesteps kernel ----------------
// LDS weight layout: 32 rows x ROWE elems; elem offset e in row r stored at
//   e ^ ((r&7)<<3)  (16B-granular XOR swizzle => conflict-free ds_read_b128).
// Read of (row=col, quad, ki) becomes offset (ki^kx)*32 + (quad^(col&3))*8.

__global__ __launch_bounds__(256, 1) void lstm_persist(
    const ushort_t* __restrict__ W1p, const ushort_t* __restrict__ W2p,
    const float* __restrict__ b1p, const float* __restrict__ b2p,
    const ushort_t* __restrict__ xemb, ushort_t* __restrict__ h1buf,
    float* __restrict__ c1, float* __restrict__ c2,
    ushort_t* __restrict__ h2a, unsigned int* bar) {
  extern __shared__ ushort_t smem[];
  int tid = threadIdx.x, wave = tid >> 6, lane = tid & 63;
  int quad = lane >> 4, col = lane & 15;
  int bx = blockIdx.x;
  int m0 = wave * 16;
  bool lower = (col & 8) == 0;
  bool isL1 = bx < 128;
  int blk = isL1 ? bx : (bx - 128);

  // ---- stage this block's 32 packed weight rows into LDS (swizzled) ----
  if (isL1) {
    const ushort_t* Wg = W1p + (long)blk * 32 * 1536;
    for (int idx = tid; idx < 32 * 192; idx += 256) {
      int r = idx / 192, e = (idx % 192) * 8;
      *(us8*)(smem + r * 1536 + (e ^ ((r & 7) << 3))) = *(const us8*)(Wg + r * 1536 + e);
    }
  } else {
    const ushort_t* Wg = W2p + (long)blk * 32 * 2048;
    for (int idx = tid; idx < 32 * 256; idx += 256) {
      int r = idx >> 8, e = (idx & 255) * 8;
      *(us8*)(smem + r * 2048 + (e ^ ((r & 7) << 3))) = *(const us8*)(Wg + r * 2048 + e);
    }
  }
  float bias0 = isL1 ? b1p[blk * 32 + col] : b2p[blk * 32 + col];
  float bias1 = isL1 ? b1p[blk * 32 + 16 + col] : b2p[blk * 32 + 16 + col];
  __syncthreads();

  int j0 = blk * 8;
  int m = m0 + col;
  int u = j0 + (col & 7);
  int q8 = (quad ^ (col & 3)) * 8;   // swizzled quad slot (elems)
  int kx = (col >> 2) & 1;           // ki LSB flip from swizzle bit 5
  const ushort_t* lw0 = isL1 ? (smem + col * 1536 + q8) : (smem + col * 2048 + q8);
  const ushort_t* lw1 = isL1 ? (smem + (col + 16) * 1536 + q8) : (smem + (col + 16) * 2048 + q8);

  for (int t = 0; t <= T_; ++t) {
    if (isL1) {
      if (t < T_) {  // ---- layer1, step t ----
        const ushort_t* h1prev = h1buf + (t & 1) * (B_ * H_);
        ushort_t* h1next = h1buf + ((t + 1) & 1) * (B_ * H_);
        const ushort_t* ar = h1prev + m * H_ + quad * 8;
        const ushort_t* xr = xemb + t * (B_ * E_) + m * E_ + quad * 8;
        f32x4 acc0 = {0.f, 0.f, 0.f, 0.f}, acc1 = {0.f, 0.f, 0.f, 0.f};
#pragma unroll 8
        for (int ki = 0; ki < 48; ++ki) {
          us8 av = (ki < 32) ? *(const us8*)(ar + ki * 32)
                             : *(const us8*)(xr + (ki - 32) * 32);
          int ks = (ki ^ kx) * 32;
          acc0 = mfma16(av, *(const us8*)(lw0 + ks), acc0);
          acc1 = mfma16(av, *(const us8*)(lw1 + ks), acc1);
        }
#pragma unroll
        for (int r = 0; r < 4; ++r) {
          float p0 = acc0[r] + bias0, p1 = acc1[r] + bias1;
          float q0 = __shfl_xor(p0, 8), q1 = __shfl_xor(p1, 8);
          if (lower) {  // p0=i, q0=f, p1=g, q1=o
            int mm = m0 + quad * 4 + r;
            float cold = c1[mm * H_ + u];
            float cn = sig_(q0) * cold + sig_(p0) * tanh_(p1);
            c1[mm * H_ + u] = cn;
            h1next[mm * H_ + u] = f2bf(sig_(q1) * tanh_(cn));
          }
        }
      }
    } else {
      if (t >= 1) {  // ---- layer2, step t2 = t-1 ----
        int t2 = t - 1;
        const ushort_t* h1cur = h1buf + ((t2 + 1) & 1) * (B_ * H_);
        const ushort_t* h2prev = h2a + t2 * (B_ * H_);
        ushort_t* h2next = h2a + (t2 + 1) * (B_ * H_);
        const ushort_t* ar = h1cur + m * H_ + quad * 8;
        const ushort_t* hr = h2prev + m * H_ + quad * 8;
        f32x4 acc0 = {0.f, 0.f, 0.f, 0.f}, acc1 = {0.f, 0.f, 0.f, 0.f};
#pragma unroll 8
        for (int ki = 0; ki < 64; ++ki) {
          us8 av = (ki < 32) ? *(const us8*)(ar + ki * 32)
                             : *(const us8*)(hr + (ki - 32) * 32);
          int ks = (ki ^ kx) * 32;
          acc0 = mfma16(av, *(const us8*)(lw0 + ks), acc0);
          acc1 = mfma16(av, *(const us8*)(lw1 + ks), acc1);
        }
#pragma unroll
        for (int r = 0; r < 4; ++r) {
          float p0 = acc0[r] + bias0, p1 = acc1[r] + bias1;
          float q0 = __shfl_xor(p0, 8), q1 = __shfl_xor(p1, 8);
          if (lower) {
            int mm = m0 + quad * 4 + r;
            float cold = c2[mm * H_ + u];
            float cn = sig_(q0) * cold + sig_(p0) * tanh_(p1);
            c2[mm * H_ + u] = cn;
            h2next[mm * H_ + u] = f2bf(sig_(q1) * tanh_(cn));
          }
        }
      }
    }
    // ---- grid barrier (skip after the final iteration) ----
    if (t < T_) {
      __syncthreads();
      if (tid == 0) {
        __threadfence();  // release: h/c writes visible device-wide
        __hip_atomic_fetch_add(bar, 1u, __ATOMIC_RELAXED, __HIP_MEMORY_SCOPE_AGENT);
        unsigned int target = 256u * (unsigned)(t + 1);  // monotonic, never reset
        while (__hip_atomic_load(bar, __ATOMIC_RELAXED, __HIP_MEMORY_SCOPE_AGENT) < target)
          __builtin_amdgcn_s_sleep(1);
        __threadfence();  // acquire: invalidate stale L1/L2 before next step's reads
      }
      __syncthreads();
    }
  }
}

// ------- output linear GEMM: C(16384 x 5120pad) = h2_all * lin_W^T + lin_b -------
// A = h2a slots 1..T (bf16, row m = t*64+b). B = lin_W fp32, converted on the fly.

__global__ __launch_bounds__(256) void gemm_out(const ushort_t* __restrict__ h2a,
                                                const float* __restrict__ linW,
                                                const float* __restrict__ linb,
                                                float* __restrict__ out) {
  __shared__ ushort_t As[128 * 40];  // stride 40 elems (80B): <=2-way LDS aliasing
  __shared__ ushort_t Bs[128 * 40];
  int tid = threadIdx.x;
  int wave = tid >> 6, lane = tid & 63, quad = lane >> 4, col = lane & 15;
  int bm = blockIdx.x & 127, bn = blockIdx.x >> 7;
  int wm = (wave & 1) * 64, wn = (wave >> 1) * 64;
  const ushort_t* Ag = h2a + B_ * H_;  // skip zero slot: row m = t*64+b

  f32x4 acc[4][4];
#pragma unroll
  for (int i = 0; i < 4; ++i)
#pragma unroll
    for (int j = 0; j < 4; ++j) acc[i][j] = f32x4{0.f, 0.f, 0.f, 0.f};

  int arow = tid >> 1, koff = (tid & 1) * 16;
  const ushort_t* ag = Ag + (bm * 128 + arow) * 1024 + koff;
  int brow = bn * 128 + arow;
  const float* bgf = linW + (long)brow * 1024 + koff;
  bool bvalid = (brow < V_);

  for (int kt = 0; kt < 32; ++kt) {
    int k0 = kt * 32;
    us8 a0 = *(const us8*)(ag + k0);
    us8 a1 = *(const us8*)(ag + k0 + 8);
    us8 b0, b1;
    if (bvalid) {
      f32x4 q0 = *(const f32x4*)(bgf + k0);
      f32x4 q1 = *(const f32x4*)(bgf + k0 + 4);
      f32x4 q2 = *(const f32x4*)(bgf + k0 + 8);
      f32x4 q3 = *(const f32x4*)(bgf + k0 + 12);
#pragma unroll
      for (int j = 0; j < 4; ++j) {
        b0[j] = f2bf(q0[j]); b0[j + 4] = f2bf(q1[j]);
        b1[j] = f2bf(q2[j]); b1[j + 4] = f2bf(q3[j]);
      }
    } else {
      b0 = us8{0, 0, 0, 0, 0, 0, 0, 0};
      b1 = us8{0, 0, 0, 0, 0, 0, 0, 0};
    }
    *(us8*)(As + arow * 40 + koff) = a0;
    *(us8*)(As + arow * 40 + koff + 8) = a1;
    *(us8*)(Bs + arow * 40 + koff) = b0;
    *(us8*)(Bs + arow * 40 + koff + 8) = b1;
    __syncthreads();
    us8 af[4], bf[4];
#pragma unroll
    for (int mi = 0; mi < 4; ++mi)
      af[mi] = *(const us8*)(As + (wm + mi * 16 + col) * 40 + quad * 8);
#pragma unroll
    for (int ni = 0; ni < 4; ++ni)
      bf[ni] = *(const us8*)(Bs + (wn + ni * 16 + col) * 40 + quad * 8);
#pragma unroll
    for (int mi = 0; mi < 4; ++mi)
#pragma unroll
      for (int ni = 0; ni < 4; ++ni) acc[mi][ni] = mfma16(af[mi], bf[ni], acc[mi][ni]);
    __syncthreads();
  }

#pragma unroll
  for (int mi = 0; mi < 4; ++mi) {
    int mgb = bm * 128 + wm + mi * 16 + quad * 4;
#pragma unroll
    for (int ni = 0; ni < 4; ++ni) {
      int ng = bn * 128 + wn + ni * 16 + col;
      if (ng < V_) {
        float lb = linb[ng];
#pragma unroll
        for (int r = 0; r < 4; ++r) {
          int m = mgb + r;          // m = t*64 + b
          int t = m >> 6, b = m & 63;
          out[b * (T_ * V_) + t * V_ + ng] = acc[mi][ni][r] + lb;
        }
      }
    }
  }
}

// ---------------- launch ----------------

extern "C" void kernel_launch(void* const* d_in, const int* in_sizes, int n_in,
                              void* d_out, int out_size, void* d_ws, size_t ws_size,
                              hipStream_t stream) {
  const int* inp = (const int*)d_in[0];
  // d_in[1] = future (always 0) — ignored
  const float* embW = (const float*)d_in[2];
  const float* Wih1 = (const float*)d_in[3];
  const float* Whh1 = (const float*)d_in[4];
  const float* bih1 = (const float*)d_in[5];
  const float* bhh1 = (const float*)d_in[6];
  const float* Wih2 = (const float*)d_in[7];
  const float* Whh2 = (const float*)d_in[8];
  const float* bih2 = (const float*)d_in[9];
  const float* bhh2 = (const float*)d_in[10];
  const float* linW = (const float*)d_in[11];
  const float* linb = (const float*)d_in[12];
  float* out = (float*)d_out;

  // staging in d_out (all dead before gemm_out writes d_out)
  unsigned int* bar = (unsigned int*)(out + OFF_BAR);
  ushort_t* W1p  = (ushort_t*)(out + OFF_W1P);
  ushort_t* W2p  = (ushort_t*)(out + OFF_W2P);
  ushort_t* xemb = (ushort_t*)(out + OFF_XEMB);
  ushort_t* h1b  = (ushort_t*)(out + OFF_H1B);
  float*    c1   = out + OFF_C1;
  float*    c2   = out + OFF_C2;
  float*    b1p  = out + OFF_B1P;
  float*    b2p  = out + OFF_B2P;

  // workspace: ONLY h2a (33.69 MB), which must be live during gemm_out
  ushort_t* h2a = (ushort_t*)d_ws;

  // allow 128KB dynamic LDS (host-side, capture-safe; call once)
  static bool s_attr_done = false;
  if (!s_attr_done) {
    (void)hipFuncSetAttribute((const void*)lstm_persist,
                              hipFuncAttributeMaxDynamicSharedMemorySize, LDS_BYTES);
    s_attr_done = true;
  }

  zero_init<<<512, 256, 0, stream>>>(h1b, c1, c2, h2a, bar);
  pack_w1<<<4096, 256, 0, stream>>>(Whh1, Wih1, bih1, bhh1, W1p, b1p);
  pack_w2<<<4096, 256, 0, stream>>>(Wih2, Whh2, bih2, bhh2, W2p, b2p);
  embed_k<<<T_ * B_, 256, 0, stream>>>(inp, embW, xemb);

  lstm_persist<<<256, 256, LDS_BYTES, stream>>>(W1p, W2p, b1p, b2p, xemb, h1b, c1, c2,
                                                h2a, bar);

  gemm_out<<<128 * 40, 256, 0, stream>>>(h2a, linW, linb, out);
}

// Round 2
// 7652.537 us; speedup vs baseline: 1.2439x; 1.2439x over previous
//
#include <hip/hip_runtime.h>

// 2-layer LSTM LM. V=5000 H=1024 E=512 B=64 T=256, future=0.
// Round-5: persistent kernel kept; barrier rebuilt as a contention-free flag array.
//   - Round-4's single atomic counter caused cross-XCD RMW ping-pong (~34us/step,
//     MfmaUtil 2.2%). Now: block bx release-stores t+1 to flags[bx] (own 64B line);
//     all 256 threads poll one flag each + __syncthreads_and. No RMW anywhere.
//   - Fences: one release(agent) (wbl2) before the flag store, one acquire(agent)
//     (buffer_inv) after the barrier. Same coherence protocol round-4 validated.
//   - c1/c2 moved to registers (block-private: each block only touches its own 8
//     columns) -- removes a dependent global load from every step's epilogue.
//   - Weights in LDS (XOR-swizzled), pack/embed/gemm_out unchanged.
// d_ws usage: ONLY h2a = (T+1)*B*H bf16 = 33.69 MB.

#define V_ 5000
#define H_ 1024
#define E_ 512
#define B_ 64
#define T_ 256

// float-element offsets into d_out for staging that is dead before gemm_out.
// out_size = B*T*V = 81,920,000 floats; regions below fit exactly at the tail.
#define OFF_FLAGS 70000000  // 4096 u32 (256 flags spaced 64B) barrier flag array
#define OFF_W1P  70180864   // 6,291,456 bf16  (4096x1536)
#define OFF_W2P  73326592   // 8,388,608 bf16  (4096x2048)
#define OFF_XEMB 77520896   // 8,388,608 bf16  (T*B*E)
#define OFF_H1B  81715200   // 131,072 bf16    (2 x B x H double buffer)
#define OFF_B1P  81911808   // 4,096 fp32
#define OFF_B2P  81915904   // 4,096 fp32      (ends exactly at 81,920,000)

#define LDS_BYTES 131072

typedef unsigned short ushort_t;
typedef __bf16 bf16x8 __attribute__((ext_vector_type(8)));
typedef unsigned short us8 __attribute__((ext_vector_type(8)));
typedef float f32x4 __attribute__((ext_vector_type(4)));

__device__ __forceinline__ ushort_t f2bf(float f) {  // RNE fp32->bf16
  unsigned int u = __float_as_uint(f);
  u += 0x7fffu + ((u >> 16) & 1u);
  return (ushort_t)(u >> 16);
}

__device__ __forceinline__ f32x4 mfma16(us8 a, us8 b, f32x4 c) {
  return __builtin_amdgcn_mfma_f32_16x16x32_bf16(
      __builtin_bit_cast(bf16x8, a), __builtin_bit_cast(bf16x8, b), c, 0, 0, 0);
}

__device__ __forceinline__ float sig_(float x) { return 1.f / (1.f + __expf(-x)); }
__device__ __forceinline__ float tanh_(float x) { return 2.f / (1.f + __expf(-2.f * x)) - 1.f; }

// ---------------- prep kernels ----------------

__global__ void zero_init(ushort_t* h1buf, ushort_t* h2s0, unsigned int* flags) {
  int i = blockIdx.x * 256 + threadIdx.x;     // grid 512*256 = 131072
  if (i < 2 * B_ * H_) h1buf[i] = 0;
  if (i < B_ * H_) h2s0[i] = 0;
  if (i < 4096) flags[i] = 0u;                // re-zeroed every graph replay
}

// packed row p: blk=p>>5 owns units blk*8..+7; rl=p&31 = tile*16 + half*8 + (u&7),
// gate g = tile*2+half (0=i 1=f 2=g 3=o). Layer1 cols: [0,1024)=W_hh1, [1024,1536)=W_ih1.
__global__ void pack_w1(const float* __restrict__ Whh, const float* __restrict__ Wih,
                        const float* __restrict__ bi, const float* __restrict__ bh,
                        ushort_t* __restrict__ W1p, float* __restrict__ b1p) {
  int p = blockIdx.x;
  int rl = p & 31, blk = p >> 5;
  int g = ((rl >> 4) << 1) | ((rl >> 3) & 1);
  int u = (blk << 3) | (rl & 7);
  int sr = g * 1024 + u;
  for (int k = threadIdx.x; k < 1536; k += 256) {
    float v = (k < 1024) ? Whh[sr * 1024 + k] : Wih[sr * 512 + (k - 1024)];
    W1p[p * 1536 + k] = f2bf(v);
  }
  if (threadIdx.x == 0) b1p[p] = bi[sr] + bh[sr];
}

// Layer2 cols: [0,1024)=W_ih2 (input h1_t), [1024,2048)=W_hh2 (h2_{t-1}).
__global__ void pack_w2(const float* __restrict__ Wih, const float* __restrict__ Whh,
                        const float* __restrict__ bi, const float* __restrict__ bh,
                        ushort_t* __restrict__ W2p, float* __restrict__ b2p) {
  int p = blockIdx.x;
  int rl = p & 31, blk = p >> 5;
  int g = ((rl >> 4) << 1) | ((rl >> 3) & 1);
  int u = (blk << 3) | (rl & 7);
  int sr = g * 1024 + u;
  for (int k = threadIdx.x; k < 2048; k += 256) {
    float v = (k < 1024) ? Wih[sr * 1024 + k] : Whh[sr * 1024 + (k - 1024)];
    W2p[p * 2048 + k] = f2bf(v);
  }
  if (threadIdx.x == 0) b2p[p] = bi[sr] + bh[sr];
}

__global__ void embed_k(const int* __restrict__ inp, const float* __restrict__ emb,
                        ushort_t* __restrict__ xemb) {
  int tb = blockIdx.x;           // tb = t*64 + b
  int t = tb >> 6, b = tb & 63;
  int tok = inp[b * T_ + t];
  const float* src = emb + (long)tok * E_;
  ushort_t* dst = xemb + (long)tb * E_;
  for (int k = threadIdx.x; k < E_; k += 256) dst[k] = f2bf(src[k]);
}

// ---------------- persistent all-timesteps kernel ----------------
// LDS weight layout: 32 rows x ROWE elems; elem offset e in row r stored at
//   e ^ ((r&7)<<3)  (16B-granular XOR swizzle => low-conflict ds_read_b128).
// Read of (row=col, quad, ki) becomes offset (ki^kx)*32 + (quad^(col&3))*8.

__global__ __launch_bounds__(256, 1) void lstm_persist(
    const ushort_t* __restrict__ W1p, const ushort_t* __restrict__ W2p,
    const float* __restrict__ b1p, const float* __restrict__ b2p,
    const ushort_t* __restrict__ xemb, ushort_t* __restrict__ h1buf,
    ushort_t* __restrict__ h2a, unsigned int* flags) {
  extern __shared__ ushort_t smem[];
  int tid = threadIdx.x, wave = tid >> 6, lane = tid & 63;
  int quad = lane >> 4, col = lane & 15;
  int bx = blockIdx.x;
  int m0 = wave * 16;
  bool lower = (col & 8) == 0;
  bool isL1 = bx < 128;
  int blk = isL1 ? bx : (bx - 128);

  // ---- stage this block's 32 packed weight rows into LDS (swizzled) ----
  if (isL1) {
    const ushort_t* Wg = W1p + (long)blk * 32 * 1536;
    for (int idx = tid; idx < 32 * 192; idx += 256) {
      int r = idx / 192, e = (idx % 192) * 8;
      *(us8*)(smem + r * 1536 + (e ^ ((r & 7) << 3))) = *(const us8*)(Wg + r * 1536 + e);
    }
  } else {
    const ushort_t* Wg = W2p + (long)blk * 32 * 2048;
    for (int idx = tid; idx < 32 * 256; idx += 256) {
      int r = idx >> 8, e = (idx & 255) * 8;
      *(us8*)(smem + r * 2048 + (e ^ ((r & 7) << 3))) = *(const us8*)(Wg + r * 2048 + e);
    }
  }
  float bias0 = isL1 ? b1p[blk * 32 + col] : b2p[blk * 32 + col];
  float bias1 = isL1 ? b1p[blk * 32 + 16 + col] : b2p[blk * 32 + 16 + col];
  __syncthreads();

  int j0 = blk * 8;
  int m = m0 + col;
  int u = j0 + (col & 7);
  int q8 = (quad ^ (col & 3)) * 8;   // swizzled quad slot (elems)
  int kx = (col >> 2) & 1;           // ki LSB flip from swizzle bit 5
  const ushort_t* lw0 = isL1 ? (smem + col * 1536 + q8) : (smem + col * 2048 + q8);
  const ushort_t* lw1 = isL1 ? (smem + (col + 16) * 1536 + q8) : (smem + (col + 16) * 2048 + q8);

  // block-private cell state in registers (valid in 'lower' lanes)
  f32x4 creg = {0.f, 0.f, 0.f, 0.f};

  for (int t = 0; t <= T_; ++t) {
    if (isL1) {
      if (t < T_) {  // ---- layer1, step t ----
        const ushort_t* h1prev = h1buf + (t & 1) * (B_ * H_);
        ushort_t* h1next = h1buf + ((t + 1) & 1) * (B_ * H_);
        const ushort_t* ar = h1prev + m * H_ + quad * 8;
        const ushort_t* xr = xemb + t * (B_ * E_) + m * E_ + quad * 8;
        f32x4 acc0 = {0.f, 0.f, 0.f, 0.f}, acc1 = {0.f, 0.f, 0.f, 0.f};
#pragma unroll 8
        for (int ki = 0; ki < 48; ++ki) {
          us8 av = (ki < 32) ? *(const us8*)(ar + ki * 32)
                             : *(const us8*)(xr + (ki - 32) * 32);
          int ks = (ki ^ kx) * 32;
          acc0 = mfma16(av, *(const us8*)(lw0 + ks), acc0);
          acc1 = mfma16(av, *(const us8*)(lw1 + ks), acc1);
        }
#pragma unroll
        for (int r = 0; r < 4; ++r) {
          float p0 = acc0[r] + bias0, p1 = acc1[r] + bias1;
          float q0 = __shfl_xor(p0, 8), q1 = __shfl_xor(p1, 8);
          float cn = sig_(q0) * creg[r] + sig_(p0) * tanh_(p1);
          creg[r] = lower ? cn : 0.f;
          if (lower) {  // p0=i, q0=f, p1=g, q1=o
            int mm = m0 + quad * 4 + r;
            h1next[mm * H_ + u] = f2bf(sig_(q1) * tanh_(cn));
          }
        }
      }
    } else {
      if (t >= 1) {  // ---- layer2, step t2 = t-1 ----
        int t2 = t - 1;
        const ushort_t* h1cur = h1buf + ((t2 + 1) & 1) * (B_ * H_);
        const ushort_t* h2prev = h2a + t2 * (B_ * H_);
        ushort_t* h2next = h2a + (t2 + 1) * (B_ * H_);
        const ushort_t* ar = h1cur + m * H_ + quad * 8;
        const ushort_t* hr = h2prev + m * H_ + quad * 8;
        f32x4 acc0 = {0.f, 0.f, 0.f, 0.f}, acc1 = {0.f, 0.f, 0.f, 0.f};
#pragma unroll 8
        for (int ki = 0; ki < 64; ++ki) {
          us8 av = (ki < 32) ? *(const us8*)(ar + ki * 32)
                             : *(const us8*)(hr + (ki - 32) * 32);
          int ks = (ki ^ kx) * 32;
          acc0 = mfma16(av, *(const us8*)(lw0 + ks), acc0);
          acc1 = mfma16(av, *(const us8*)(lw1 + ks), acc1);
        }
#pragma unroll
        for (int r = 0; r < 4; ++r) {
          float p0 = acc0[r] + bias0, p1 = acc1[r] + bias1;
          float q0 = __shfl_xor(p0, 8), q1 = __shfl_xor(p1, 8);
          float cn = sig_(q0) * creg[r] + sig_(p0) * tanh_(p1);
          creg[r] = lower ? cn : 0.f;
          if (lower) {
            int mm = m0 + quad * 4 + r;
            h2next[mm * H_ + u] = f2bf(sig_(q1) * tanh_(cn));
          }
        }
      }
    }
    // ---- contention-free grid barrier (skip after the final iteration) ----
    if (t < T_) {
      __syncthreads();  // all waves' h-stores drained to L2 (waitcnt before s_barrier)
      if (tid == 0) {
        __builtin_amdgcn_fence(__ATOMIC_RELEASE, "agent");  // wbl2: L2 -> coherence pt
        __hip_atomic_store(&flags[bx * 16], (unsigned)(t + 1), __ATOMIC_RELAXED,
                           __HIP_MEMORY_SCOPE_AGENT);
      }
      unsigned tgt = (unsigned)(t + 1);
      int done;
      do {
        unsigned f = __hip_atomic_load(&flags[tid * 16], __ATOMIC_RELAXED,
                                       __HIP_MEMORY_SCOPE_AGENT);
        done = __syncthreads_and((int)(f >= tgt));
        if (!done) __builtin_amdgcn_s_sleep(8);
      } while (!done);
      __builtin_amdgcn_fence(__ATOMIC_ACQUIRE, "agent");  // inv stale L1/L2
    }
  }
}

// ------- output linear GEMM: C(16384 x 5120pad) = h2_all * lin_W^T + lin_b -------
// A = h2a slots 1..T (bf16, row m = t*64+b). B = lin_W fp32, converted on the fly.

__global__ __launch_bounds__(256) void gemm_out(const ushort_t* __restrict__ h2a,
                                                const float* __restrict__ linW,
                                                const float* __restrict__ linb,
                                                float* __restrict__ out) {
  __shared__ ushort_t As[128 * 40];  // stride 40 elems (80B): <=2-way LDS aliasing
  __shared__ ushort_t Bs[128 * 40];
  int tid = threadIdx.x;
  int wave = tid >> 6, lane = tid & 63, quad = lane >> 4, col = lane & 15;
  int bm = blockIdx.x & 127, bn = blockIdx.x >> 7;
  int wm = (wave & 1) * 64, wn = (wave >> 1) * 64;
  const ushort_t* Ag = h2a + B_ * H_;  // skip zero slot: row m = t*64+b

  f32x4 acc[4][4];
#pragma unroll
  for (int i = 0; i < 4; ++i)
#pragma unroll
    for (int j = 0; j < 4; ++j) acc[i][j] = f32x4{0.f, 0.f, 0.f, 0.f};

  int arow = tid >> 1, koff = (tid & 1) * 16;
  const ushort_t* ag = Ag + (bm * 128 + arow) * 1024 + koff;
  int brow = bn * 128 + arow;
  const float* bgf = linW + (long)brow * 1024 + koff;
  bool bvalid = (brow < V_);

  for (int kt = 0; kt < 32; ++kt) {
    int k0 = kt * 32;
    us8 a0 = *(const us8*)(ag + k0);
    us8 a1 = *(const us8*)(ag + k0 + 8);
    us8 b0, b1;
    if (bvalid) {
      f32x4 q0 = *(const f32x4*)(bgf + k0);
      f32x4 q1 = *(const f32x4*)(bgf + k0 + 4);
      f32x4 q2 = *(const f32x4*)(bgf + k0 + 8);
      f32x4 q3 = *(const f32x4*)(bgf + k0 + 12);
#pragma unroll
      for (int j = 0; j < 4; ++j) {
        b0[j] = f2bf(q0[j]); b0[j + 4] = f2bf(q1[j]);
        b1[j] = f2bf(q2[j]); b1[j + 4] = f2bf(q3[j]);
      }
    } else {
      b0 = us8{0, 0, 0, 0, 0, 0, 0, 0};
      b1 = us8{0, 0, 0, 0, 0, 0, 0, 0};
    }
    *(us8*)(As + arow * 40 + koff) = a0;
    *(us8*)(As + arow * 40 + koff + 8) = a1;
    *(us8*)(Bs + arow * 40 + koff) = b0;
    *(us8*)(Bs + arow * 40 + koff + 8) = b1;
    __syncthreads();
    us8 af[4], bf[4];
#pragma unroll
    for (int mi = 0; mi < 4; ++mi)
      af[mi] = *(const us8*)(As + (wm + mi * 16 + col) * 40 + quad * 8);
#pragma unroll
    for (int ni = 0; ni < 4; ++ni)
      bf[ni] = *(const us8*)(Bs + (wn + ni * 16 + col) * 40 + quad * 8);
#pragma unroll
    for (int mi = 0; mi < 4; ++mi)
#pragma unroll
      for (int ni = 0; ni < 4; ++ni) acc[mi][ni] = mfma16(af[mi], bf[ni], acc[mi][ni]);
    __syncthreads();
  }

#pragma unroll
  for (int mi = 0; mi < 4; ++mi) {
    int mgb = bm * 128 + wm + mi * 16 + quad * 4;
#pragma unroll
    for (int ni = 0; ni < 4; ++ni) {
      int ng = bn * 128 + wn + ni * 16 + col;
      if (ng < V_) {
        float lb = linb[ng];
#pragma unroll
        for (int r = 0; r < 4; ++r) {
          int m = mgb + r;          // m = t*64 + b
          int t = m >> 6, b = m & 63;
          out[b * (T_ * V_) + t * V_ + ng] = acc[mi][ni][r] + lb;
        }
      }
    }
  }
}

// ---------------- launch ----------------

extern "C" void kernel_launch(void* const* d_in, const int* in_sizes, int n_in,
                              void* d_out, int out_size, void* d_ws, size_t ws_size,
                              hipStream_t stream) {
  const int* inp = (const int*)d_in[0];
  // d_in[1] = future (always 0) — ignored
  const float* embW = (const float*)d_in[2];
  const float* Wih1 = (const float*)d_in[3];
  const float* Whh1 = (const float*)d_in[4];
  const float* bih1 = (const float*)d_in[5];
  const float* bhh1 = (const float*)d_in[6];
  const float* Wih2 = (const float*)d_in[7];
  const float* Whh2 = (const float*)d_in[8];
  const float* bih2 = (const float*)d_in[9];
  const float* bhh2 = (const float*)d_in[10];
  const float* linW = (const float*)d_in[11];
  const float* linb = (const float*)d_in[12];
  float* out = (float*)d_out;

  // staging in d_out (all dead before gemm_out writes d_out)
  unsigned int* flags = (unsigned int*)(out + OFF_FLAGS);
  ushort_t* W1p  = (ushort_t*)(out + OFF_W1P);
  ushort_t* W2p  = (ushort_t*)(out + OFF_W2P);
  ushort_t* xemb = (ushort_t*)(out + OFF_XEMB);
  ushort_t* h1b  = (ushort_t*)(out + OFF_H1B);
  float*    b1p  = out + OFF_B1P;
  float*    b2p  = out + OFF_B2P;

  // workspace: ONLY h2a (33.69 MB), which must be live during gemm_out
  ushort_t* h2a = (ushort_t*)d_ws;

  // allow 128KB dynamic LDS (host-side, capture-safe; call once)
  static bool s_attr_done = false;
  if (!s_attr_done) {
    (void)hipFuncSetAttribute((const void*)lstm_persist,
                              hipFuncAttributeMaxDynamicSharedMemorySize, LDS_BYTES);
    s_attr_done = true;
  }

  zero_init<<<512, 256, 0, stream>>>(h1b, h2a, flags);
  pack_w1<<<4096, 256, 0, stream>>>(Whh1, Wih1, bih1, bhh1, W1p, b1p);
  pack_w2<<<4096, 256, 0, stream>>>(Wih2, Whh2, bih2, bhh2, W2p, b2p);
  embed_k<<<T_ * B_, 256, 0, stream>>>(inp, embW, xemb);

  lstm_persist<<<256, 256, LDS_BYTES, stream>>>(W1p, W2p, b1p, b2p, xemb, h1b, h2a,
                                                flags);

  gemm_out<<<128 * 40, 256, 0, stream>>>(h2a, linW, linb, out);
}

// Round 3
// 5262.951 us; speedup vs baseline: 1.8087x; 1.4540x over previous
//
#include <hip/hip_runtime.h>

// 2-layer LSTM LM. V=5000 H=1024 E=512 B=64 T=256, future=0.
// Round-6: fence-free persistent kernel.
//   - Round-5 post-mortem: the agent fences (buffer_wbl2 / buffer_inv = full L2 tag
//     walks, every block, every step) were the 27us/step cost, not the atomic.
//   - Coherence now by construction: h1 is a (T+1)-slot rotating buffer (h2a already
//     was). Every step reads fresh addresses no cache ever held -> plain cached loads
//     are coherent. h stores are write-through (sc0 sc1) to the MALL, drained with
//     s_waitcnt vmcnt(0) before the barrier flag. NO fences anywhere.
//   - Barrier: per-block flag (own 64B line), sc0sc1 store; per-thread sc0sc1 poll
//     + one __syncthreads. No RMW, no L2 walks.
//   - LDS: XOR swizzle dropped (it only gave 4x16B spread -> 4-way conflicts,
//     SQ_LDS_BANK_CONFLICT 1.17e8). Row stride padded to 1544/2056 elems instead
//     (stride % 32 banks = 4 -> <=2-way aliasing = free). LDS = 131,584 B.
//   - pack/embed/gemm_out unchanged.
// d_ws usage: ONLY h2a = (T+1)*B*H bf16 = 33.69 MB.

#define V_ 5000
#define H_ 1024
#define E_ 512
#define B_ 64
#define T_ 256

// float-element offsets into d_out for staging that is dead before gemm_out.
// out_size = B*T*V = 81,920,000 floats.
#define OFF_H1A  61000000   // 16,842,752 bf16 = 8,421,376 floats ((T+1) x B x H)
#define OFF_FLAGS 70000000  // 4096 u32 (256 flags spaced 64B) barrier flag array
#define OFF_W1P  70180864   // 6,291,456 bf16  (4096x1536)
#define OFF_W2P  73326592   // 8,388,608 bf16  (4096x2048)
#define OFF_XEMB 77520896   // 8,388,608 bf16  (T*B*E)
#define OFF_B1P  81911808   // 4,096 fp32
#define OFF_B2P  81915904   // 4,096 fp32      (ends exactly at 81,920,000)

#define RS1 1544            // padded LDS row stride (elems), layer1 (1536+8)
#define RS2 2056            // padded LDS row stride (elems), layer2 (2048+8)
#define LDS_BYTES (32 * RS2 * 2)   // 131,584 B  (<160KB/CU, forces 1 block/CU)

typedef unsigned short ushort_t;
typedef __bf16 bf16x8 __attribute__((ext_vector_type(8)));
typedef unsigned short us8 __attribute__((ext_vector_type(8)));
typedef float f32x4 __attribute__((ext_vector_type(4)));

__device__ __forceinline__ ushort_t f2bf(float f) {  // RNE fp32->bf16
  unsigned int u = __float_as_uint(f);
  u += 0x7fffu + ((u >> 16) & 1u);
  return (ushort_t)(u >> 16);
}

__device__ __forceinline__ f32x4 mfma16(us8 a, us8 b, f32x4 c) {
  return __builtin_amdgcn_mfma_f32_16x16x32_bf16(
      __builtin_bit_cast(bf16x8, a), __builtin_bit_cast(bf16x8, b), c, 0, 0, 0);
}

__device__ __forceinline__ float sig_(float x) { return 1.f / (1.f + __expf(-x)); }
__device__ __forceinline__ float tanh_(float x) { return 2.f / (1.f + __expf(-2.f * x)) - 1.f; }

// write-through 2B store to the device coherence point (MALL)
__device__ __forceinline__ void st_cohere_b16(ushort_t* p, unsigned int v) {
  asm volatile("global_store_short %0, %1, off sc0 sc1" :: "v"(p), "v"(v) : "memory");
}
__device__ __forceinline__ void st_cohere_b32(unsigned int* p, unsigned int v) {
  asm volatile("global_store_dword %0, %1, off sc0 sc1" :: "v"(p), "v"(v) : "memory");
}
// L1/L2-bypassing 4B load from the MALL (self-draining)
__device__ __forceinline__ unsigned int ld_cohere_b32(const unsigned int* p) {
  unsigned int r;
  asm volatile("global_load_dword %0, %1, off sc0 sc1" : "=v"(r) : "v"(p) : "memory");
  asm volatile("s_waitcnt vmcnt(0)" ::: "memory");
  return r;
}

// ---------------- prep kernels ----------------

__global__ void zero_init(ushort_t* h1a, ushort_t* h2s0, unsigned int* flags) {
  int i = blockIdx.x * 256 + threadIdx.x;     // grid 512*256 = 131072
  if (i < B_ * H_) { h1a[i] = 0; h2s0[i] = 0; }   // slot-0 of both h buffers
  if (i < 4096) flags[i] = 0u;                    // re-zeroed every graph replay
}

// packed row p: blk=p>>5 owns units blk*8..+7; rl=p&31 = tile*16 + half*8 + (u&7),
// gate g = tile*2+half (0=i 1=f 2=g 3=o). Layer1 cols: [0,1024)=W_hh1, [1024,1536)=W_ih1.
__global__ void pack_w1(const float* __restrict__ Whh, const float* __restrict__ Wih,
                        const float* __restrict__ bi, const float* __restrict__ bh,
                        ushort_t* __restrict__ W1p, float* __restrict__ b1p) {
  int p = blockIdx.x;
  int rl = p & 31, blk = p >> 5;
  int g = ((rl >> 4) << 1) | ((rl >> 3) & 1);
  int u = (blk << 3) | (rl & 7);
  int sr = g * 1024 + u;
  for (int k = threadIdx.x; k < 1536; k += 256) {
    float v = (k < 1024) ? Whh[sr * 1024 + k] : Wih[sr * 512 + (k - 1024)];
    W1p[p * 1536 + k] = f2bf(v);
  }
  if (threadIdx.x == 0) b1p[p] = bi[sr] + bh[sr];
}

// Layer2 cols: [0,1024)=W_ih2 (input h1_t), [1024,2048)=W_hh2 (h2_{t-1}).
__global__ void pack_w2(const float* __restrict__ Wih, const float* __restrict__ Whh,
                        const float* __restrict__ bi, const float* __restrict__ bh,
                        ushort_t* __restrict__ W2p, float* __restrict__ b2p) {
  int p = blockIdx.x;
  int rl = p & 31, blk = p >> 5;
  int g = ((rl >> 4) << 1) | ((rl >> 3) & 1);
  int u = (blk << 3) | (rl & 7);
  int sr = g * 1024 + u;
  for (int k = threadIdx.x; k < 2048; k += 256) {
    float v = (k < 1024) ? Wih[sr * 1024 + k] : Whh[sr * 1024 + (k - 1024)];
    W2p[p * 2048 + k] = f2bf(v);
  }
  if (threadIdx.x == 0) b2p[p] = bi[sr] + bh[sr];
}

__global__ void embed_k(const int* __restrict__ inp, const float* __restrict__ emb,
                        ushort_t* __restrict__ xemb) {
  int tb = blockIdx.x;           // tb = t*64 + b
  int t = tb >> 6, b = tb & 63;
  int tok = inp[b * T_ + t];
  const float* src = emb + (long)tok * E_;
  ushort_t* dst = xemb + (long)tb * E_;
  for (int k = threadIdx.x; k < E_; k += 256) dst[k] = f2bf(src[k]);
}

// ---------------- persistent all-timesteps kernel ----------------

__global__ __launch_bounds__(256, 1) void lstm_persist(
    const ushort_t* __restrict__ W1p, const ushort_t* __restrict__ W2p,
    const float* __restrict__ b1p, const float* __restrict__ b2p,
    const ushort_t* __restrict__ xemb, ushort_t* __restrict__ h1a,
    ushort_t* __restrict__ h2a, unsigned int* flags) {
  extern __shared__ ushort_t smem[];
  int tid = threadIdx.x, wave = tid >> 6, lane = tid & 63;
  int quad = lane >> 4, col = lane & 15;
  int bx = blockIdx.x;
  int m0 = wave * 16;
  bool lower = (col & 8) == 0;
  bool isL1 = bx < 128;
  int blk = isL1 ? bx : (bx - 128);

  // ---- stage this block's 32 packed weight rows into LDS (padded stride) ----
  if (isL1) {
    const ushort_t* Wg = W1p + (long)blk * 32 * 1536;
    for (int idx = tid; idx < 32 * 192; idx += 256) {
      int r = idx / 192, e = (idx % 192) * 8;
      *(us8*)(smem + r * RS1 + e) = *(const us8*)(Wg + r * 1536 + e);
    }
  } else {
    const ushort_t* Wg = W2p + (long)blk * 32 * 2048;
    for (int idx = tid; idx < 32 * 256; idx += 256) {
      int r = idx >> 8, e = (idx & 255) * 8;
      *(us8*)(smem + r * RS2 + e) = *(const us8*)(Wg + r * 2048 + e);
    }
  }
  float bias0 = isL1 ? b1p[blk * 32 + col] : b2p[blk * 32 + col];
  float bias1 = isL1 ? b1p[blk * 32 + 16 + col] : b2p[blk * 32 + 16 + col];
  __syncthreads();

  int j0 = blk * 8;
  int m = m0 + col;
  int u = j0 + (col & 7);
  const int RS = isL1 ? RS1 : RS2;
  const ushort_t* lw0 = smem + col * RS + quad * 8;
  const ushort_t* lw1 = smem + (col + 16) * RS + quad * 8;

  // block-private cell state in registers (valid in 'lower' lanes)
  f32x4 creg = {0.f, 0.f, 0.f, 0.f};

  for (int t = 0; t <= T_; ++t) {
    if (isL1) {
      if (t < T_) {  // ---- layer1, step t ----
        const ushort_t* h1prev = h1a + (long)t * (B_ * H_);       // fresh slot: cached OK
        ushort_t* h1next = h1a + (long)(t + 1) * (B_ * H_);
        const ushort_t* ar = h1prev + m * H_ + quad * 8;
        const ushort_t* xr = xemb + t * (B_ * E_) + m * E_ + quad * 8;
        f32x4 acc0 = {0.f, 0.f, 0.f, 0.f}, acc1 = {0.f, 0.f, 0.f, 0.f};
#pragma unroll 16
        for (int ki = 0; ki < 48; ++ki) {
          us8 av = (ki < 32) ? *(const us8*)(ar + ki * 32)
                             : *(const us8*)(xr + (ki - 32) * 32);
          acc0 = mfma16(av, *(const us8*)(lw0 + ki * 32), acc0);
          acc1 = mfma16(av, *(const us8*)(lw1 + ki * 32), acc1);
        }
#pragma unroll
        for (int r = 0; r < 4; ++r) {
          float p0 = acc0[r] + bias0, p1 = acc1[r] + bias1;
          float q0 = __shfl_xor(p0, 8), q1 = __shfl_xor(p1, 8);
          float cn = sig_(q0) * creg[r] + sig_(p0) * tanh_(p1);
          creg[r] = lower ? cn : 0.f;
          if (lower) {  // p0=i, q0=f, p1=g, q1=o
            int mm = m0 + quad * 4 + r;
            st_cohere_b16(h1next + mm * H_ + u, (unsigned)f2bf(sig_(q1) * tanh_(cn)));
          }
        }
      }
    } else {
      if (t >= 1) {  // ---- layer2, step t2 = t-1 ----
        int t2 = t - 1;
        const ushort_t* h1cur = h1a + (long)(t2 + 1) * (B_ * H_);  // fresh slot
        const ushort_t* h2prev = h2a + (long)t2 * (B_ * H_);       // fresh slot
        ushort_t* h2next = h2a + (long)(t2 + 1) * (B_ * H_);
        const ushort_t* ar = h1cur + m * H_ + quad * 8;
        const ushort_t* hr = h2prev + m * H_ + quad * 8;
        f32x4 acc0 = {0.f, 0.f, 0.f, 0.f}, acc1 = {0.f, 0.f, 0.f, 0.f};
#pragma unroll 16
        for (int ki = 0; ki < 64; ++ki) {
          us8 av = (ki < 32) ? *(const us8*)(ar + ki * 32)
                             : *(const us8*)(hr + (ki - 32) * 32);
          acc0 = mfma16(av, *(const us8*)(lw0 + ki * 32), acc0);
          acc1 = mfma16(av, *(const us8*)(lw1 + ki * 32), acc1);
        }
#pragma unroll
        for (int r = 0; r < 4; ++r) {
          float p0 = acc0[r] + bias0, p1 = acc1[r] + bias1;
          float q0 = __shfl_xor(p0, 8), q1 = __shfl_xor(p1, 8);
          float cn = sig_(q0) * creg[r] + sig_(p0) * tanh_(p1);
          creg[r] = lower ? cn : 0.f;
          if (lower) {
            int mm = m0 + quad * 4 + r;
            st_cohere_b16(h2next + mm * H_ + u, (unsigned)f2bf(sig_(q1) * tanh_(cn)));
          }
        }
      }
    }
    // ---- fence-free grid barrier (skip after the final iteration) ----
    if (t < T_) {
      // drain this wave's write-through h stores to the MALL, then block-barrier
      asm volatile("s_waitcnt vmcnt(0)" ::: "memory");
      __syncthreads();
      if (tid == 0) st_cohere_b32(&flags[bx * 16], (unsigned)(t + 1));
      unsigned tgt = (unsigned)(t + 1);
      while (ld_cohere_b32(&flags[tid * 16]) < tgt) __builtin_amdgcn_s_sleep(2);
      __syncthreads();
    }
  }
}

// ------- output linear GEMM: C(16384 x 5120pad) = h2_all * lin_W^T + lin_b -------
// A = h2a slots 1..T (bf16, row m = t*64+b). B = lin_W fp32, converted on the fly.

__global__ __launch_bounds__(256) void gemm_out(const ushort_t* __restrict__ h2a,
                                                const float* __restrict__ linW,
                                                const float* __restrict__ linb,
                                                float* __restrict__ out) {
  __shared__ ushort_t As[128 * 40];  // stride 40 elems (80B): <=2-way LDS aliasing
  __shared__ ushort_t Bs[128 * 40];
  int tid = threadIdx.x;
  int wave = tid >> 6, lane = tid & 63, quad = lane >> 4, col = lane & 15;
  int bm = blockIdx.x & 127, bn = blockIdx.x >> 7;
  int wm = (wave & 1) * 64, wn = (wave >> 1) * 64;
  const ushort_t* Ag = h2a + B_ * H_;  // skip zero slot: row m = t*64+b

  f32x4 acc[4][4];
#pragma unroll
  for (int i = 0; i < 4; ++i)
#pragma unroll
    for (int j = 0; j < 4; ++j) acc[i][j] = f32x4{0.f, 0.f, 0.f, 0.f};

  int arow = tid >> 1, koff = (tid & 1) * 16;
  const ushort_t* ag = Ag + (bm * 128 + arow) * 1024 + koff;
  int brow = bn * 128 + arow;
  const float* bgf = linW + (long)brow * 1024 + koff;
  bool bvalid = (brow < V_);

  for (int kt = 0; kt < 32; ++kt) {
    int k0 = kt * 32;
    us8 a0 = *(const us8*)(ag + k0);
    us8 a1 = *(const us8*)(ag + k0 + 8);
    us8 b0, b1;
    if (bvalid) {
      f32x4 q0 = *(const f32x4*)(bgf + k0);
      f32x4 q1 = *(const f32x4*)(bgf + k0 + 4);
      f32x4 q2 = *(const f32x4*)(bgf + k0 + 8);
      f32x4 q3 = *(const f32x4*)(bgf + k0 + 12);
#pragma unroll
      for (int j = 0; j < 4; ++j) {
        b0[j] = f2bf(q0[j]); b0[j + 4] = f2bf(q1[j]);
        b1[j] = f2bf(q2[j]); b1[j + 4] = f2bf(q3[j]);
      }
    } else {
      b0 = us8{0, 0, 0, 0, 0, 0, 0, 0};
      b1 = us8{0, 0, 0, 0, 0, 0, 0, 0};
    }
    *(us8*)(As + arow * 40 + koff) = a0;
    *(us8*)(As + arow * 40 + koff + 8) = a1;
    *(us8*)(Bs + arow * 40 + koff) = b0;
    *(us8*)(Bs + arow * 40 + koff + 8) = b1;
    __syncthreads();
    us8 af[4], bf[4];
#pragma unroll
    for (int mi = 0; mi < 4; ++mi)
      af[mi] = *(const us8*)(As + (wm + mi * 16 + col) * 40 + quad * 8);
#pragma unroll
    for (int ni = 0; ni < 4; ++ni)
      bf[ni] = *(const us8*)(Bs + (wn + ni * 16 + col) * 40 + quad * 8);
#pragma unroll
    for (int mi = 0; mi < 4; ++mi)
#pragma unroll
      for (int ni = 0; ni < 4; ++ni) acc[mi][ni] = mfma16(af[mi], bf[ni], acc[mi][ni]);
    __syncthreads();
  }

#pragma unroll
  for (int mi = 0; mi < 4; ++mi) {
    int mgb = bm * 128 + wm + mi * 16 + quad * 4;
#pragma unroll
    for (int ni = 0; ni < 4; ++ni) {
      int ng = bn * 128 + wn + ni * 16 + col;
      if (ng < V_) {
        float lb = linb[ng];
#pragma unroll
        for (int r = 0; r < 4; ++r) {
          int m = mgb + r;          // m = t*64 + b
          int t = m >> 6, b = m & 63;
          out[b * (T_ * V_) + t * V_ + ng] = acc[mi][ni][r] + lb;
        }
      }
    }
  }
}

// ---------------- launch ----------------

extern "C" void kernel_launch(void* const* d_in, const int* in_sizes, int n_in,
                              void* d_out, int out_size, void* d_ws, size_t ws_size,
                              hipStream_t stream) {
  const int* inp = (const int*)d_in[0];
  // d_in[1] = future (always 0) — ignored
  const float* embW = (const float*)d_in[2];
  const float* Wih1 = (const float*)d_in[3];
  const float* Whh1 = (const float*)d_in[4];
  const float* bih1 = (const float*)d_in[5];
  const float* bhh1 = (const float*)d_in[6];
  const float* Wih2 = (const float*)d_in[7];
  const float* Whh2 = (const float*)d_in[8];
  const float* bih2 = (const float*)d_in[9];
  const float* bhh2 = (const float*)d_in[10];
  const float* linW = (const float*)d_in[11];
  const float* linb = (const float*)d_in[12];
  float* out = (float*)d_out;

  // staging in d_out (all dead before gemm_out writes d_out)
  ushort_t* h1a  = (ushort_t*)(out + OFF_H1A);
  unsigned int* flags = (unsigned int*)(out + OFF_FLAGS);
  ushort_t* W1p  = (ushort_t*)(out + OFF_W1P);
  ushort_t* W2p  = (ushort_t*)(out + OFF_W2P);
  ushort_t* xemb = (ushort_t*)(out + OFF_XEMB);
  float*    b1p  = out + OFF_B1P;
  float*    b2p  = out + OFF_B2P;

  // workspace: ONLY h2a (33.69 MB), which must be live during gemm_out
  ushort_t* h2a = (ushort_t*)d_ws;

  // allow >64KB dynamic LDS (host-side, capture-safe; call once)
  static bool s_attr_done = false;
  if (!s_attr_done) {
    (void)hipFuncSetAttribute((const void*)lstm_persist,
                              hipFuncAttributeMaxDynamicSharedMemorySize, LDS_BYTES);
    s_attr_done = true;
  }

  zero_init<<<512, 256, 0, stream>>>(h1a, h2a, flags);
  pack_w1<<<4096, 256, 0, stream>>>(Whh1, Wih1, bih1, bhh1, W1p, b1p);
  pack_w2<<<4096, 256, 0, stream>>>(Wih2, Whh2, bih2, bhh2, W2p, b2p);
  embed_k<<<T_ * B_, 256, 0, stream>>>(inp, embW, xemb);

  lstm_persist<<<256, 256, LDS_BYTES, stream>>>(W1p, W2p, b1p, b2p, xemb, h1a, h2a,
                                                flags);

  gemm_out<<<128 * 40, 256, 0, stream>>>(h2a, linW, linb, out);
}